// Round 1
// baseline (175.247 us; speedup 1.0000x reference)
//
#include <hip/hip_runtime.h>
#include <math.h>

#define BB 2
#define NN 384
#define DD 256
#define HH 8
#define HDD 32
#define SMROW 388            // padded row stride (floats) for e-matrix rows; 388*4B = 16B-aligned
#define INV_SQRT_HD 0.17677669529663687f   // 1/sqrt(32)

// ---------------- Kernel 1: QKV projection ----------------
// x:(B,N,256)  w:(768,256)  b:(768)
// outputs q,k,v each in (B,H,N,32) layout
__global__ __launch_bounds__(256) void qkv_kernel(
    const float* __restrict__ x, const float* __restrict__ w,
    const float* __restrict__ bias,
    float* __restrict__ qb, float* __restrict__ kb, float* __restrict__ vb)
{
    const int ROWS = 4;
    int r0 = blockIdx.x * ROWS;
    __shared__ float xs[ROWS][DD];
    int tid = threadIdx.x;
#pragma unroll
    for (int rr = 0; rr < ROWS; ++rr)
        xs[rr][tid] = x[(r0 + rr) * DD + tid];
    __syncthreads();

    int h = tid >> 5, d = tid & 31;
#pragma unroll
    for (int part = 0; part < 3; ++part) {
        int o = part * 256 + tid;
        const float4* wrow = (const float4*)(w + o * DD);
        float a0 = 0.f, a1 = 0.f, a2 = 0.f, a3 = 0.f;
        for (int c4 = 0; c4 < DD / 4; ++c4) {
            float4 wv = wrow[c4];
            int c = c4 * 4;
            float4 x0 = *(const float4*)&xs[0][c];
            float4 x1 = *(const float4*)&xs[1][c];
            float4 x2 = *(const float4*)&xs[2][c];
            float4 x3 = *(const float4*)&xs[3][c];
            a0 += wv.x * x0.x + wv.y * x0.y + wv.z * x0.z + wv.w * x0.w;
            a1 += wv.x * x1.x + wv.y * x1.y + wv.z * x1.z + wv.w * x1.w;
            a2 += wv.x * x2.x + wv.y * x2.y + wv.z * x2.z + wv.w * x2.w;
            a3 += wv.x * x3.x + wv.y * x3.y + wv.z * x3.z + wv.w * x3.w;
        }
        float bo = bias[o];
        float* dst = (part == 0) ? qb : (part == 1) ? kb : vb;
        float acc[ROWS] = {a0 + bo, a1 + bo, a2 + bo, a3 + bo};
#pragma unroll
        for (int rr = 0; rr < ROWS; ++rr) {
            int row = r0 + rr;
            int b = row / NN, n = row - b * NN;
            dst[(((b * HH + h) * NN) + n) * HDD + d] = acc[rr];
        }
    }
}

__device__ __forceinline__ float silu_f(float v) {
    return v * __builtin_amdgcn_rcpf(1.0f + __expf(-v));
}

// ---------------- Kernel 2: fused scores + softmax + context ----------------
// one block per (b,i); 384 threads = 6 waves
__global__ __launch_bounds__(384) void attn_kernel(
    const float* __restrict__ coords,
    const float* __restrict__ rb_w1, const float* __restrict__ rb_b1,
    const float* __restrict__ rb_w2, const float* __restrict__ rb_b2,
    const float* __restrict__ rv_w1, const float* __restrict__ rv_b1,
    const float* __restrict__ rv_w2, const float* __restrict__ rv_b2,
    const float* __restrict__ qb, const float* __restrict__ kb,
    const float* __restrict__ vb, float* __restrict__ out)
{
    __shared__ float qs[256];               // q row, all heads
    __shared__ float sm[HH * SMROW];        // unnormalized softmax e-values [8][388]
    __shared__ float4 rel4[NN];             // rel coords per j
    __shared__ float redmax[6][8];
    __shared__ float redsum[6][8];
    __shared__ float uni[3072];             // 12KB union

    float* rbw  = uni;          // phase1: [256][4] = {w1x,w1y,w1z,b1}
    float* w2s  = uni + 1024;   // phase1: rb_w2 [8][256]
    float* Tlds = uni;          // phase2: [8][256]
    float* baseS = uni + 2048;  // phase2: [256]

    int tid = threadIdx.x;
    int bx = blockIdx.x;
    int b = bx / NN, i = bx - b * NN;

    // ---- loads ----
    if (tid < 256) {
        int hq = tid >> 5, dq = tid & 31;
        qs[tid] = qb[(((b * HH + hq) * NN) + i) * HDD + dq];
        rbw[tid * 4 + 0] = rb_w1[tid * 3 + 0];
        rbw[tid * 4 + 1] = rb_w1[tid * 3 + 1];
        rbw[tid * 4 + 2] = rb_w1[tid * 3 + 2];
        rbw[tid * 4 + 3] = rb_b1[tid];
    }
    for (int idx = tid; idx < 2048; idx += 384) w2s[idx] = rb_w2[idx];

    int j = tid;
    float cix = coords[(b * NN + i) * 3 + 0];
    float ciy = coords[(b * NN + i) * 3 + 1];
    float ciz = coords[(b * NN + i) * 3 + 2];
    float rx = cix - coords[(b * NN + j) * 3 + 0];
    float ry = ciy - coords[(b * NN + j) * 3 + 1];
    float rz = ciz - coords[(b * NN + j) * 3 + 2];
    rel4[j] = make_float4(rx, ry, rz, 0.f);
    __syncthreads();

    // ---- phase 1: rel_bias MLP + q.k -> 8 scores in registers ----
    float sc[8];
#pragma unroll
    for (int h = 0; h < 8; ++h) sc[h] = rb_b2[h];

    for (int c = 0; c < 256; c += 4) {
        float4 wa = *(const float4*)&rbw[(c + 0) * 4];
        float4 wb = *(const float4*)&rbw[(c + 1) * 4];
        float4 wc = *(const float4*)&rbw[(c + 2) * 4];
        float4 wd = *(const float4*)&rbw[(c + 3) * 4];
        float s0 = silu_f(fmaf(rx, wa.x, fmaf(ry, wa.y, fmaf(rz, wa.z, wa.w))));
        float s1 = silu_f(fmaf(rx, wb.x, fmaf(ry, wb.y, fmaf(rz, wb.z, wb.w))));
        float s2 = silu_f(fmaf(rx, wc.x, fmaf(ry, wc.y, fmaf(rz, wc.z, wc.w))));
        float s3 = silu_f(fmaf(rx, wd.x, fmaf(ry, wd.y, fmaf(rz, wd.z, wd.w))));
#pragma unroll
        for (int h = 0; h < 8; ++h) {
            float4 ww = *(const float4*)&w2s[h * 256 + c];
            sc[h] += s0 * ww.x + s1 * ww.y + s2 * ww.z + s3 * ww.w;
        }
    }

#pragma unroll
    for (int h = 0; h < 8; ++h) {
        const float4* kp = (const float4*)(kb + (((b * HH + h) * NN) + j) * HDD);
        float acc = 0.f;
#pragma unroll
        for (int dd = 0; dd < 8; ++dd) {
            float4 kv = kp[dd];
            float4 qv = *(const float4*)&qs[h * 32 + dd * 4];
            acc += kv.x * qv.x + kv.y * qv.y + kv.z * qv.z + kv.w * qv.w;
        }
        sc[h] = fmaf(acc, INV_SQRT_HD, sc[h]);
    }

    // ---- softmax over j (all 8 head-rows at once) ----
    int wv = tid >> 6, lane = tid & 63;
    float mx[8];
#pragma unroll
    for (int h = 0; h < 8; ++h) mx[h] = sc[h];
#pragma unroll
    for (int off = 32; off; off >>= 1) {
#pragma unroll
        for (int h = 0; h < 8; ++h)
            mx[h] = fmaxf(mx[h], __shfl_xor(mx[h], off));
    }
    if (lane == 0) {
#pragma unroll
        for (int h = 0; h < 8; ++h) redmax[wv][h] = mx[h];
    }
    __syncthreads();
#pragma unroll
    for (int h = 0; h < 8; ++h) {
        float m = redmax[0][h];
#pragma unroll
        for (int w = 1; w < 6; ++w) m = fmaxf(m, redmax[w][h]);
        mx[h] = m;
    }
    float ss[8];
#pragma unroll
    for (int h = 0; h < 8; ++h) {
        float e = __expf(sc[h] - mx[h]);
        sm[h * SMROW + j] = e;
        ss[h] = e;
    }
#pragma unroll
    for (int off = 32; off; off >>= 1) {
#pragma unroll
        for (int h = 0; h < 8; ++h)
            ss[h] += __shfl_xor(ss[h], off);
    }
    if (lane == 0) {
#pragma unroll
        for (int h = 0; h < 8; ++h) redsum[wv][h] = ss[h];
    }
    __syncthreads();   // sm[] + redsum[] now valid; uni[] free for reuse

    // ---- phase 2 ----
    if (tid < 256) {
        // group A: T[h][c] = sum_j e[h][j] * silu(rel_j . rv_w1[c] + rv_b1[c])
        int c = tid;
        float w1x = rv_w1[c * 3 + 0], w1y = rv_w1[c * 3 + 1], w1z = rv_w1[c * 3 + 2];
        float b1v = rv_b1[c];
        float T0=0,T1=0,T2=0,T3=0,T4=0,T5=0,T6=0,T7=0;
        for (int jj = 0; jj < NN; jj += 4) {
            float4 r0 = rel4[jj + 0], r1 = rel4[jj + 1], r2 = rel4[jj + 2], r3 = rel4[jj + 3];
            float4 e0 = *(const float4*)&sm[0 * SMROW + jj];
            float4 e1 = *(const float4*)&sm[1 * SMROW + jj];
            float4 e2 = *(const float4*)&sm[2 * SMROW + jj];
            float4 e3 = *(const float4*)&sm[3 * SMROW + jj];
            float4 e4 = *(const float4*)&sm[4 * SMROW + jj];
            float4 e5 = *(const float4*)&sm[5 * SMROW + jj];
            float4 e6 = *(const float4*)&sm[6 * SMROW + jj];
            float4 e7 = *(const float4*)&sm[7 * SMROW + jj];
            float s0 = silu_f(fmaf(r0.x, w1x, fmaf(r0.y, w1y, fmaf(r0.z, w1z, b1v))));
            float s1 = silu_f(fmaf(r1.x, w1x, fmaf(r1.y, w1y, fmaf(r1.z, w1z, b1v))));
            float s2 = silu_f(fmaf(r2.x, w1x, fmaf(r2.y, w1y, fmaf(r2.z, w1z, b1v))));
            float s3 = silu_f(fmaf(r3.x, w1x, fmaf(r3.y, w1y, fmaf(r3.z, w1z, b1v))));
            T0 += e0.x*s0 + e0.y*s1 + e0.z*s2 + e0.w*s3;
            T1 += e1.x*s0 + e1.y*s1 + e1.z*s2 + e1.w*s3;
            T2 += e2.x*s0 + e2.y*s1 + e2.z*s2 + e2.w*s3;
            T3 += e3.x*s0 + e3.y*s1 + e3.z*s2 + e3.w*s3;
            T4 += e4.x*s0 + e4.y*s1 + e4.z*s2 + e4.w*s3;
            T5 += e5.x*s0 + e5.y*s1 + e5.z*s2 + e5.w*s3;
            T6 += e6.x*s0 + e6.y*s1 + e6.z*s2 + e6.w*s3;
            T7 += e7.x*s0 + e7.y*s1 + e7.z*s2 + e7.w*s3;
        }
        Tlds[0 * 256 + c] = T0;  Tlds[1 * 256 + c] = T1;
        Tlds[2 * 256 + c] = T2;  Tlds[3 * 256 + c] = T3;
        Tlds[4 * 256 + c] = T4;  Tlds[5 * 256 + c] = T5;
        Tlds[6 * 256 + c] = T6;  Tlds[7 * 256 + c] = T7;
    } else {
        // group B: base[h][d] = (sum_j e[h][j] * v[b,h,j,d]) / Z[h]
        int t = tid - 256;
#pragma unroll
        for (int rep = 0; rep < 2; ++rep) {
            int o = t + rep * 128;
            int h = o >> 5, d = o & 31;
            const float* vp = vb + (((b * HH + h) * NN) * HDD) + d;
            float acc = 0.f;
            for (int jj = 0; jj < NN; jj += 4) {
                float4 ev = *(const float4*)&sm[h * SMROW + jj];
                acc += ev.x * vp[(jj + 0) * HDD] + ev.y * vp[(jj + 1) * HDD]
                     + ev.z * vp[(jj + 2) * HDD] + ev.w * vp[(jj + 3) * HDD];
            }
            float z = redsum[0][h] + redsum[1][h] + redsum[2][h]
                    + redsum[3][h] + redsum[4][h] + redsum[5][h];
            baseS[o] = acc * __builtin_amdgcn_rcpf(z);
        }
    }
    __syncthreads();

    // ---- final: rc = (T @ rv_w2^T)/Z ;  out = base + rc + rv_b2 ----
    if (tid < 256) {
        int o = tid, h = o >> 5;
        const float4* w2p = (const float4*)(rv_w2 + o * 256);
        float acc = 0.f;
        for (int cc = 0; cc < 64; ++cc) {
            float4 wvv = w2p[cc];
            float4 tv = *(const float4*)&Tlds[h * 256 + cc * 4];
            acc += wvv.x * tv.x + wvv.y * tv.y + wvv.z * tv.z + wvv.w * tv.w;
        }
        float z = redsum[0][h] + redsum[1][h] + redsum[2][h]
                + redsum[3][h] + redsum[4][h] + redsum[5][h];
        out[(b * NN + i) * DD + o] = fmaf(acc, __builtin_amdgcn_rcpf(z), baseS[o]) + rv_b2[o];
    }
}

extern "C" void kernel_launch(void* const* d_in, const int* in_sizes, int n_in,
                              void* d_out, int out_size, void* d_ws, size_t ws_size,
                              hipStream_t stream) {
    const float* x      = (const float*)d_in[0];
    const float* coords = (const float*)d_in[1];
    const float* qkv_w  = (const float*)d_in[2];
    const float* qkv_b  = (const float*)d_in[3];
    const float* rb_w1  = (const float*)d_in[4];
    const float* rb_b1  = (const float*)d_in[5];
    const float* rb_w2  = (const float*)d_in[6];
    const float* rb_b2  = (const float*)d_in[7];
    const float* rv_w1  = (const float*)d_in[8];
    const float* rv_b1  = (const float*)d_in[9];
    const float* rv_w2  = (const float*)d_in[10];
    const float* rv_b2  = (const float*)d_in[11];
    float* out = (float*)d_out;

    float* ws = (float*)d_ws;
    const int PER = BB * HH * NN * HDD;   // 196608 floats
    float* qb = ws;
    float* kb = ws + PER;
    float* vb = ws + 2 * PER;

    qkv_kernel<<<(BB * NN) / 4, 256, 0, stream>>>(x, qkv_w, qkv_b, qb, kb, vb);
    attn_kernel<<<BB * NN, 384, 0, stream>>>(coords,
        rb_w1, rb_b1, rb_w2, rb_b2, rv_w1, rv_b1, rv_w2, rv_b2,
        qb, kb, vb, out);
}

// Round 2
// 148.618 us; speedup vs baseline: 1.1792x; 1.1792x over previous
//
#include <hip/hip_runtime.h>
#include <math.h>

#define BB 2
#define NN 384
#define DD 256
#define HH 8
#define HDD 32
#define INV_SQRT_HD 0.17677669529663687f   // 1/sqrt(32)

#define SM_ST 388   // f32 stride, scores/e rows
#define EA_ST 392   // bf16 stride, e A-frag rows
#define W2_ST 264   // bf16 stride, rb_w2 rows
#define T_ST  264   // f32 stride, T rows

typedef float f32x4 __attribute__((ext_vector_type(4)));
typedef __bf16 bf16x8 __attribute__((ext_vector_type(8)));

__device__ __forceinline__ float silu_f(float v) {
    return v * __builtin_amdgcn_rcpf(1.0f + __expf(-v));
}

__device__ __forceinline__ f32x4 mfma16(bf16x8 a, bf16x8 b, f32x4 c) {
    return __builtin_amdgcn_mfma_f32_16x16x32_bf16(a, b, c, 0, 0, 0);
}

// 8 hidden evals: silu(ap[q] - av[q]) -> bf16 frag (vector ap from LDS float4s)
__device__ __forceinline__ bf16x8 hid8(bf16x8 av, float4 a0, float4 a1) {
    bf16x8 r;
    r[0] = (__bf16)silu_f(a0.x - (float)av[0]);
    r[1] = (__bf16)silu_f(a0.y - (float)av[1]);
    r[2] = (__bf16)silu_f(a0.z - (float)av[2]);
    r[3] = (__bf16)silu_f(a0.w - (float)av[3]);
    r[4] = (__bf16)silu_f(a1.x - (float)av[4]);
    r[5] = (__bf16)silu_f(a1.y - (float)av[5]);
    r[6] = (__bf16)silu_f(a1.z - (float)av[6]);
    r[7] = (__bf16)silu_f(a1.w - (float)av[7]);
    return r;
}
// 8 hidden evals with scalar ap (phase 2: c fixed per lane)
__device__ __forceinline__ bf16x8 hid8s(bf16x8 av, float a) {
    bf16x8 r;
#pragma unroll
    for (int q = 0; q < 8; ++q) r[q] = (__bf16)silu_f(a - (float)av[q]);
    return r;
}

// ---------------- Kernel 0: A-array precompute ----------------
// Arb[r][c] = coords_r . rb_w1_c   (bf16, [768][256])
// ArvT[c][r] = coords_r . rv_w1_c  (bf16, [256][768])
__global__ __launch_bounds__(256) void pre_kernel(
    const float* __restrict__ coords,
    const float* __restrict__ rb_w1, const float* __restrict__ rv_w1,
    __bf16* __restrict__ Arb, __bf16* __restrict__ ArvT)
{
    int r = blockIdx.x, c = threadIdx.x;
    float cx = coords[r * 3 + 0], cy = coords[r * 3 + 1], cz = coords[r * 3 + 2];
    float ab = cx * rb_w1[c * 3 + 0] + cy * rb_w1[c * 3 + 1] + cz * rb_w1[c * 3 + 2];
    float av = cx * rv_w1[c * 3 + 0] + cy * rv_w1[c * 3 + 1] + cz * rv_w1[c * 3 + 2];
    Arb[r * DD + c] = (__bf16)ab;
    ArvT[c * (BB * NN) + r] = (__bf16)av;
}

// ---------------- Kernel 1: QKV projection (unchanged) ----------------
__global__ __launch_bounds__(256) void qkv_kernel(
    const float* __restrict__ x, const float* __restrict__ w,
    const float* __restrict__ bias,
    float* __restrict__ qb, float* __restrict__ kb, float* __restrict__ vb)
{
    const int ROWS = 4;
    int r0 = blockIdx.x * ROWS;
    __shared__ float xs[ROWS][DD];
    int tid = threadIdx.x;
#pragma unroll
    for (int rr = 0; rr < ROWS; ++rr)
        xs[rr][tid] = x[(r0 + rr) * DD + tid];
    __syncthreads();

    int h = tid >> 5, d = tid & 31;
#pragma unroll
    for (int part = 0; part < 3; ++part) {
        int o = part * 256 + tid;
        const float4* wrow = (const float4*)(w + o * DD);
        float a0 = 0.f, a1 = 0.f, a2 = 0.f, a3 = 0.f;
        for (int c4 = 0; c4 < DD / 4; ++c4) {
            float4 wv = wrow[c4];
            int c = c4 * 4;
            float4 x0 = *(const float4*)&xs[0][c];
            float4 x1 = *(const float4*)&xs[1][c];
            float4 x2 = *(const float4*)&xs[2][c];
            float4 x3 = *(const float4*)&xs[3][c];
            a0 += wv.x * x0.x + wv.y * x0.y + wv.z * x0.z + wv.w * x0.w;
            a1 += wv.x * x1.x + wv.y * x1.y + wv.z * x1.z + wv.w * x1.w;
            a2 += wv.x * x2.x + wv.y * x2.y + wv.z * x2.z + wv.w * x2.w;
            a3 += wv.x * x3.x + wv.y * x3.y + wv.z * x3.z + wv.w * x3.w;
        }
        float bo = bias[o];
        float* dst = (part == 0) ? qb : (part == 1) ? kb : vb;
        float acc[ROWS] = {a0 + bo, a1 + bo, a2 + bo, a3 + bo};
#pragma unroll
        for (int rr = 0; rr < ROWS; ++rr) {
            int row = r0 + rr;
            int b = row / NN, n = row - b * NN;
            dst[(((b * HH + h) * NN) + n) * HDD + d] = acc[rr];
        }
    }
}

// ---------------- Kernel 2: fused attention, MFMA MLP second layers ----------------
// one block per (b,i); 512 threads = 8 waves
__global__ __launch_bounds__(512, 4) void attn_kernel(
    const float* __restrict__ rb_b1, const float* __restrict__ rb_w2,
    const float* __restrict__ rb_b2,
    const float* __restrict__ rv_b1, const float* __restrict__ rv_w2,
    const float* __restrict__ rv_b2,
    const float* __restrict__ qb, const float* __restrict__ kb,
    const float* __restrict__ vb,
    const __bf16* __restrict__ Arb, const __bf16* __restrict__ ArvT,
    float* __restrict__ out)
{
    __shared__ __align__(16) float qs[256];
    __shared__ __align__(16) float Apr[256];          // Arb[i][:] + rb_b1
    __shared__ __align__(16) float Apv[256];          // Arv[i][:] + rv_b1
    __shared__ __align__(16) __bf16 w2bf[HH * W2_ST]; // rb_w2 bf16
    __shared__ __align__(16) float sc_e[HH * SM_ST];  // scores -> e (f32)
    __shared__ __align__(16) __bf16 eAbf[HH * EA_ST]; // e bf16 A-frag rows
    __shared__ __align__(16) float Tl[HH * T_ST];     // T[h][c]
    __shared__ float redmax[6][8];
    __shared__ float redsum[6][8];
    __shared__ __align__(16) float basep[2][256];

    int tid = threadIdx.x;
    int bx = blockIdx.x;
    int b = bx / NN, i = bx - b * NN;

    // ---- setup ----
    if (tid < 256) {
        int hq = tid >> 5, dq = tid & 31;
        qs[tid] = qb[(((b * HH + hq) * NN) + i) * HDD + dq];
        Apr[tid] = (float)Arb[(b * NN + i) * DD + tid] + rb_b1[tid];
        Apv[tid] = (float)ArvT[tid * (BB * NN) + b * NN + i] + rv_b1[tid];
    }
    for (int idx = tid; idx < HH * 256; idx += 512)
        w2bf[(idx >> 8) * W2_ST + (idx & 255)] = (__bf16)rb_w2[idx];
    __syncthreads();

    int l = tid & 63, wv = tid >> 6;
    int lr = l & 15, lg = l >> 4;

    // ---- phase 1: rel_bias via MFMA. M-tiles wv, wv+8, wv+16 ----
    {
        f32x4 acc0 = {0.f, 0.f, 0.f, 0.f}, acc1 = acc0, acc2 = acc0;
        const __bf16* arb = Arb + (size_t)b * NN * DD;
        const __bf16* arow0 = arb + ((wv      ) * 16 + lr) * DD;
        const __bf16* arow1 = arb + ((wv +  8) * 16 + lr) * DD;
        const __bf16* arow2 = arb + ((wv + 16) * 16 + lr) * DD;
#pragma unroll
        for (int ks = 0; ks < 8; ++ks) {
            int c0 = ks * 32 + lg * 8;
            float4 a0 = *(const float4*)&Apr[c0];
            float4 a1 = *(const float4*)&Apr[c0 + 4];
            bf16x8 bf = *(const bf16x8*)&w2bf[(lr & 7) * W2_ST + c0];
            bf16x8 v0 = *(const bf16x8*)(arow0 + c0);
            bf16x8 v1 = *(const bf16x8*)(arow1 + c0);
            bf16x8 v2 = *(const bf16x8*)(arow2 + c0);
            acc0 = mfma16(hid8(v0, a0, a1), bf, acc0);
            acc1 = mfma16(hid8(v1, a0, a1), bf, acc1);
            acc2 = mfma16(hid8(v2, a0, a1), bf, acc2);
        }
        // D: col = h = lr (<8 real), row j = tile*16 + lg*4 + r
        if (lr < HH) {
#pragma unroll
            for (int r = 0; r < 4; ++r) {
                int jr = lg * 4 + r;
                sc_e[lr * SM_ST + (wv      ) * 16 + jr] = acc0[r];
                sc_e[lr * SM_ST + (wv +  8) * 16 + jr] = acc1[r];
                sc_e[lr * SM_ST + (wv + 16) * 16 + jr] = acc2[r];
            }
        }
    }
    __syncthreads();

    // ---- QK^T (fp32 VALU) + softmax: threads 0..383 own j ----
    float sc[8];
    if (tid < NN) {
        int j = tid;
#pragma unroll
        for (int h = 0; h < 8; ++h) {
            const float4* kp = (const float4*)(kb + (((b * HH + h) * NN) + j) * HDD);
            float a = 0.f;
#pragma unroll
            for (int dd = 0; dd < 8; ++dd) {
                float4 kv = kp[dd];
                float4 qv = *(const float4*)&qs[h * 32 + dd * 4];
                a += kv.x * qv.x + kv.y * qv.y + kv.z * qv.z + kv.w * qv.w;
            }
            sc[h] = sc_e[h * SM_ST + j] + a * INV_SQRT_HD + rb_b2[h];
        }
        float mx[8];
#pragma unroll
        for (int h = 0; h < 8; ++h) mx[h] = sc[h];
#pragma unroll
        for (int off = 32; off; off >>= 1)
#pragma unroll
            for (int h = 0; h < 8; ++h)
                mx[h] = fmaxf(mx[h], __shfl_xor(mx[h], off));
        if (l == 0)
#pragma unroll
            for (int h = 0; h < 8; ++h) redmax[wv][h] = mx[h];
    }
    __syncthreads();
    if (tid < NN) {
        int j = tid;
        float ss[8];
#pragma unroll
        for (int h = 0; h < 8; ++h) {
            float m = redmax[0][h];
#pragma unroll
            for (int w = 1; w < 6; ++w) m = fmaxf(m, redmax[w][h]);
            float e = __expf(sc[h] - m);
            sc_e[h * SM_ST + j] = e;
            eAbf[h * EA_ST + j] = (__bf16)e;
            ss[h] = e;
        }
#pragma unroll
        for (int off = 32; off; off >>= 1)
#pragma unroll
            for (int h = 0; h < 8; ++h)
                ss[h] += __shfl_xor(ss[h], off);
        if (l == 0)
#pragma unroll
            for (int h = 0; h < 8; ++h) redsum[wv][h] = ss[h];
    }
    __syncthreads();

    // ---- phase 2: T[h][c] via MFMA. N-tiles wv, wv+8; K over j ----
    {
        f32x4 p0 = {0.f, 0.f, 0.f, 0.f}, p1 = p0;
        int c0 = wv * 16 + lr, c1 = (wv + 8) * 16 + lr;
        float ap0 = Apv[c0], ap1 = Apv[c1];
        const __bf16* vrow0 = ArvT + (size_t)c0 * (BB * NN) + b * NN;
        const __bf16* vrow1 = ArvT + (size_t)c1 * (BB * NN) + b * NN;
#pragma unroll
        for (int ks = 0; ks < 12; ++ks) {
            int j0 = ks * 32 + lg * 8;
            bf16x8 ef = *(const bf16x8*)&eAbf[(lr & 7) * EA_ST + j0];
            bf16x8 h0 = hid8s(*(const bf16x8*)(vrow0 + j0), ap0);
            bf16x8 h1 = hid8s(*(const bf16x8*)(vrow1 + j0), ap1);
            p0 = mfma16(ef, h0, p0);
            p1 = mfma16(ef, h1, p1);
        }
        // D: col = c = tile*16+lr, row = h = lg*4 + r (only lg<2 real)
        if (lg < 2) {
#pragma unroll
            for (int r = 0; r < 4; ++r) {
                int h = lg * 4 + r;
                Tl[h * T_ST + wv * 16 + lr]       = p0[r];
                Tl[h * T_ST + (wv + 8) * 16 + lr] = p1[r];
            }
        }
    }

    // ---- base path: base[h][d] partials (runs on all 512 threads) ----
    {
        int o = tid & 255, hf = tid >> 8;
        int hB = o >> 5, dB = o & 31;
        const float* vp = vb + (((size_t)(b * HH + hB) * NN) + hf * 192) * HDD + dB;
        const float* ep = &sc_e[hB * SM_ST + hf * 192];
        float accB = 0.f;
        for (int jj = 0; jj < 192; jj += 4) {
            float4 ev = *(const float4*)&ep[jj];
            accB += ev.x * vp[(jj + 0) * HDD] + ev.y * vp[(jj + 1) * HDD]
                  + ev.z * vp[(jj + 2) * HDD] + ev.w * vp[(jj + 3) * HDD];
        }
        basep[hf][o] = accB;
    }
    __syncthreads();

    // ---- epilogue: rc = T @ rv_w2^T; out = (base + rc)/Z + rv_b2 ----
    if (tid < 256) {
        int o = tid, h = o >> 5;
        float z = redsum[0][h] + redsum[1][h] + redsum[2][h]
                + redsum[3][h] + redsum[4][h] + redsum[5][h];
        const float4* w2p = (const float4*)(rv_w2 + (size_t)o * DD);
        float a = 0.f;
#pragma unroll 4
        for (int cc = 0; cc < 64; ++cc) {
            float4 wv4 = w2p[cc];
            float4 tv = *(const float4*)&Tl[h * T_ST + cc * 4];
            a += wv4.x * tv.x + wv4.y * tv.y + wv4.z * tv.z + wv4.w * tv.w;
        }
        out[((size_t)(b * NN) + i) * DD + o] =
            (a + basep[0][o] + basep[1][o]) * __builtin_amdgcn_rcpf(z) + rv_b2[o];
    }
}

extern "C" void kernel_launch(void* const* d_in, const int* in_sizes, int n_in,
                              void* d_out, int out_size, void* d_ws, size_t ws_size,
                              hipStream_t stream) {
    const float* x      = (const float*)d_in[0];
    const float* coords = (const float*)d_in[1];
    const float* qkv_w  = (const float*)d_in[2];
    const float* qkv_b  = (const float*)d_in[3];
    const float* rb_w1  = (const float*)d_in[4];
    const float* rb_b1  = (const float*)d_in[5];
    const float* rb_w2  = (const float*)d_in[6];
    const float* rb_b2  = (const float*)d_in[7];
    const float* rv_w1  = (const float*)d_in[8];
    const float* rv_b1  = (const float*)d_in[9];
    const float* rv_w2  = (const float*)d_in[10];
    const float* rv_b2  = (const float*)d_in[11];
    float* out = (float*)d_out;

    float* ws = (float*)d_ws;
    const int PER = BB * HH * NN * HDD;   // 196608 floats
    float* qb = ws;
    float* kb = ws + PER;
    float* vb = ws + 2 * PER;
    __bf16* Arb  = (__bf16*)(ws + 3 * PER);
    __bf16* ArvT = Arb + BB * NN * DD;

    pre_kernel<<<BB * NN, 256, 0, stream>>>(coords, rb_w1, rv_w1, Arb, ArvT);
    qkv_kernel<<<(BB * NN) / 4, 256, 0, stream>>>(x, qkv_w, qkv_b, qb, kb, vb);
    attn_kernel<<<BB * NN, 512, 0, stream>>>(
        rb_b1, rb_w2, rb_b2, rv_b1, rv_w2, rv_b2,
        qb, kb, vb, Arb, ArvT, out);
}

// Round 3
// 118.449 us; speedup vs baseline: 1.4795x; 1.2547x over previous
//
#include <hip/hip_runtime.h>
#include <math.h>

#define BB 2
#define NN 384
#define DD 256
#define HH 8
#define INV_SQRT_HD 0.17677669529663687f   // 1/sqrt(32)

#define W2_ST 264   // bf16 stride, rb_w2 rows
#define EA_ST 392   // bf16 stride, e A-frag rows
#define T_ST  264   // f32 stride, T rows

typedef float f32x4 __attribute__((ext_vector_type(4)));
typedef __bf16 bf16x8 __attribute__((ext_vector_type(8)));
typedef __bf16 bf16x4 __attribute__((ext_vector_type(4)));

__device__ __forceinline__ float silu_f(float v) {
    return v * __builtin_amdgcn_rcpf(1.0f + __expf(-v));
}
__device__ __forceinline__ f32x4 mfma16(bf16x8 a, bf16x8 b, f32x4 c) {
    return __builtin_amdgcn_mfma_f32_16x16x32_bf16(a, b, c, 0, 0, 0);
}
// 8 hidden evals: silu(ap[q] - av[q]) (vector ap from LDS float4s)
__device__ __forceinline__ bf16x8 hid8(bf16x8 av, float4 a0, float4 a1) {
    bf16x8 r;
    r[0] = (__bf16)silu_f(a0.x - (float)av[0]);
    r[1] = (__bf16)silu_f(a0.y - (float)av[1]);
    r[2] = (__bf16)silu_f(a0.z - (float)av[2]);
    r[3] = (__bf16)silu_f(a0.w - (float)av[3]);
    r[4] = (__bf16)silu_f(a1.x - (float)av[4]);
    r[5] = (__bf16)silu_f(a1.y - (float)av[5]);
    r[6] = (__bf16)silu_f(a1.z - (float)av[6]);
    r[7] = (__bf16)silu_f(a1.w - (float)av[7]);
    return r;
}
__device__ __forceinline__ bf16x8 hid8s(bf16x8 av, float a) {
    bf16x8 r;
#pragma unroll
    for (int q = 0; q < 8; ++q) r[q] = (__bf16)silu_f(a - (float)av[q]);
    return r;
}

// ---------------- Kernel 0: A-array precompute ----------------
// Arb[r][c] = coords_r . rb_w1_c   (bf16, [768][256])
// ArvT[c][r] = coords_r . rv_w1_c  (bf16, [256][768])
__global__ __launch_bounds__(256) void pre_kernel(
    const float* __restrict__ coords,
    const float* __restrict__ rb_w1, const float* __restrict__ rv_w1,
    __bf16* __restrict__ Arb, __bf16* __restrict__ ArvT)
{
    int r = blockIdx.x, c = threadIdx.x;
    float cx = coords[r * 3 + 0], cy = coords[r * 3 + 1], cz = coords[r * 3 + 2];
    float ab = cx * rb_w1[c * 3 + 0] + cy * rb_w1[c * 3 + 1] + cz * rb_w1[c * 3 + 2];
    float av = cx * rv_w1[c * 3 + 0] + cy * rv_w1[c * 3 + 1] + cz * rv_w1[c * 3 + 2];
    Arb[r * DD + c] = (__bf16)ab;
    ArvT[c * (BB * NN) + r] = (__bf16)av;
}

// ---------------- Kernel 1: QKV projection ----------------
// q: f32 [b*N+n][256] pre-scaled by 1/sqrt(32)
// k: bf16 [b*N+n][256]  (row-major, (h,d) inner)
// vT: bf16 [b][256(hd)][384(n)]
__global__ __launch_bounds__(256) void qkv_kernel(
    const float* __restrict__ x, const float* __restrict__ w,
    const float* __restrict__ bias,
    float* __restrict__ qb, __bf16* __restrict__ kbbf, __bf16* __restrict__ vT)
{
    const int ROWS = 4;
    int r0 = blockIdx.x * ROWS;
    __shared__ float xs[ROWS][DD];
    int tid = threadIdx.x;
#pragma unroll
    for (int rr = 0; rr < ROWS; ++rr)
        xs[rr][tid] = x[(r0 + rr) * DD + tid];
    __syncthreads();

#pragma unroll
    for (int part = 0; part < 3; ++part) {
        int o = part * 256 + tid;
        const float4* wrow = (const float4*)(w + o * DD);
        float a0 = 0.f, a1 = 0.f, a2 = 0.f, a3 = 0.f;
        for (int c4 = 0; c4 < DD / 4; ++c4) {
            float4 wv = wrow[c4];
            int c = c4 * 4;
            float4 x0 = *(const float4*)&xs[0][c];
            float4 x1 = *(const float4*)&xs[1][c];
            float4 x2 = *(const float4*)&xs[2][c];
            float4 x3 = *(const float4*)&xs[3][c];
            a0 += wv.x * x0.x + wv.y * x0.y + wv.z * x0.z + wv.w * x0.w;
            a1 += wv.x * x1.x + wv.y * x1.y + wv.z * x1.z + wv.w * x1.w;
            a2 += wv.x * x2.x + wv.y * x2.y + wv.z * x2.z + wv.w * x2.w;
            a3 += wv.x * x3.x + wv.y * x3.y + wv.z * x3.z + wv.w * x3.w;
        }
        float bo = bias[o];
        float acc[ROWS] = {a0 + bo, a1 + bo, a2 + bo, a3 + bo};
#pragma unroll
        for (int rr = 0; rr < ROWS; ++rr) {
            int row = r0 + rr;            // b*NN + n
            int b = row / NN, n = row - b * NN;
            if (part == 0) qb[row * DD + tid] = acc[rr] * INV_SQRT_HD;
            else if (part == 1) kbbf[row * DD + tid] = (__bf16)acc[rr];
            else vT[(size_t)b * DD * NN + (size_t)tid * NN + n] = (__bf16)acc[rr];
        }
    }
}

// ---------------- Kernel 2: fused attention, 2 i's per block ----------------
__global__ __launch_bounds__(512, 4) void attn_kernel(
    const float* __restrict__ rb_b1, const float* __restrict__ rb_w2,
    const float* __restrict__ rb_b2,
    const float* __restrict__ rv_b1, const float* __restrict__ rv_w2,
    const float* __restrict__ rv_b2,
    const float* __restrict__ qb, const __bf16* __restrict__ kbbf,
    const __bf16* __restrict__ vT,
    const __bf16* __restrict__ Arb, const __bf16* __restrict__ ArvT,
    float* __restrict__ out)
{
    __shared__ __align__(16) float qs[2][DD];
    __shared__ __align__(16) float Apr[2][DD];
    __shared__ __align__(16) float Apv[2][DD];
    __shared__ __align__(16) __bf16 w2bf[HH * W2_ST];
    __shared__ __align__(16) __bf16 eAbf[2][HH * EA_ST];
    __shared__ __align__(16) float Tl[2][HH * T_ST];
    __shared__ __align__(16) float basep[2][DD];
    __shared__ float redsum[8][2][HH];

    int tid = threadIdx.x;
    int bx = blockIdx.x;
    int b = bx / (NN / 2);
    int i0 = (bx - b * (NN / 2)) * 2;

    // ---- setup ----
    if (tid < 256) {
#pragma unroll
        for (int i = 0; i < 2; ++i) {
            int gi = b * NN + i0 + i;
            qs[i][tid]  = qb[gi * DD + tid];
            Apr[i][tid] = (float)Arb[gi * DD + tid] + rb_b1[tid];
            Apv[i][tid] = (float)ArvT[(size_t)tid * (BB * NN) + gi] + rv_b1[tid];
        }
    }
    for (int idx = tid; idx < HH * 256; idx += 512)
        w2bf[(idx >> 8) * W2_ST + (idx & 255)] = (__bf16)rb_w2[idx];
    __syncthreads();

    int l = tid & 63, wv = tid >> 6;
    int lr = l & 15, lg = l >> 4;
    float rb2l = rb_b2[lr & 7];

    // ---- phase 1: scores = rel_bias (hid@w2) + QK (block-diag MFMA) ----
    {
        const __bf16* arbB = Arb + (size_t)b * NN * DD;
        const __bf16* kbB  = kbbf + (size_t)b * NN * DD;
        const __bf16* ar0 = arbB + ((wv     ) * 16 + lr) * DD;
        const __bf16* ar1 = arbB + ((wv +  8) * 16 + lr) * DD;
        const __bf16* ar2 = arbB + ((wv + 16) * 16 + lr) * DD;
        const __bf16* kr0 = kbB  + ((wv     ) * 16 + lr) * DD;
        const __bf16* kr1 = kbB  + ((wv +  8) * 16 + lr) * DD;
        const __bf16* kr2 = kbB  + ((wv + 16) * 16 + lr) * DD;
        f32x4 a00 = {0.f,0.f,0.f,0.f}, a01 = a00, a10 = a00, a11 = a00, a20 = a00, a21 = a00;
#pragma unroll
        for (int ks = 0; ks < 8; ++ks) {
            int c0 = ks * 32 + lg * 8;
            float4 p00 = *(const float4*)&Apr[0][c0];
            float4 p01 = *(const float4*)&Apr[0][c0 + 4];
            float4 p10 = *(const float4*)&Apr[1][c0];
            float4 p11 = *(const float4*)&Apr[1][c0 + 4];
            bf16x8 wf = *(const bf16x8*)&w2bf[(lr & 7) * W2_ST + c0];
            bf16x8 v0 = *(const bf16x8*)(ar0 + c0);
            bf16x8 v1 = *(const bf16x8*)(ar1 + c0);
            bf16x8 v2 = *(const bf16x8*)(ar2 + c0);
            bf16x8 k0 = *(const bf16x8*)(kr0 + c0);
            bf16x8 k1 = *(const bf16x8*)(kr1 + c0);
            bf16x8 k2 = *(const bf16x8*)(kr2 + c0);
            bf16x8 qf0, qf1;
#pragma unroll
            for (int e = 0; e < 8; ++e) { qf0[e] = (__bf16)0.f; qf1[e] = (__bf16)0.f; }
            if (lr == ks) {
#pragma unroll
                for (int e = 0; e < 8; ++e) {
                    qf0[e] = (__bf16)qs[0][c0 + e];
                    qf1[e] = (__bf16)qs[1][c0 + e];
                }
            }
            a00 = mfma16(hid8(v0, p00, p01), wf, a00);
            a01 = mfma16(hid8(v0, p10, p11), wf, a01);
            a10 = mfma16(hid8(v1, p00, p01), wf, a10);
            a11 = mfma16(hid8(v1, p10, p11), wf, a11);
            a20 = mfma16(hid8(v2, p00, p01), wf, a20);
            a21 = mfma16(hid8(v2, p10, p11), wf, a21);
            a00 = mfma16(k0, qf0, a00);
            a01 = mfma16(k0, qf1, a01);
            a10 = mfma16(k1, qf0, a10);
            a11 = mfma16(k1, qf1, a11);
            a20 = mfma16(k2, qf0, a20);
            a21 = mfma16(k2, qf1, a21);
        }

        // e = exp(score + rb_b2), Z partials, write e (bf16) to LDS
        float z0 = 0.f, z1 = 0.f;
#define FINTILE(ACC, I, T, ZACC) { \
            float e0 = __expf(ACC[0] + rb2l); \
            float e1 = __expf(ACC[1] + rb2l); \
            float e2 = __expf(ACC[2] + rb2l); \
            float e3 = __expf(ACC[3] + rb2l); \
            if (lr < 8) { \
                bf16x4 ev; \
                ev[0] = (__bf16)e0; ev[1] = (__bf16)e1; \
                ev[2] = (__bf16)e2; ev[3] = (__bf16)e3; \
                *(bf16x4*)&eAbf[I][lr * EA_ST + (wv + (T) * 8) * 16 + lg * 4] = ev; \
            } \
            float zs = e0 + e1 + e2 + e3; \
            zs += __shfl_xor(zs, 16); \
            zs += __shfl_xor(zs, 32); \
            ZACC += zs; }
        FINTILE(a00, 0, 0, z0)
        FINTILE(a10, 0, 1, z0)
        FINTILE(a20, 0, 2, z0)
        FINTILE(a01, 1, 0, z1)
        FINTILE(a11, 1, 1, z1)
        FINTILE(a21, 1, 2, z1)
#undef FINTILE
        if (lg == 0 && lr < 8) {
            redsum[wv][0][lr] = z0;
            redsum[wv][1][lr] = z1;
        }
    }
    __syncthreads();

    // ---- phase 2: T[h][c] (hid) and base[h][d] (vT) via MFMA, K = j ----
    {
        int c0 = wv * 16 + lr, c1 = (wv + 8) * 16 + lr;
        float ap00 = Apv[0][c0], ap01 = Apv[0][c1];
        float ap10 = Apv[1][c0], ap11 = Apv[1][c1];
        const __bf16* vr0 = ArvT + (size_t)c0 * (BB * NN) + b * NN;
        const __bf16* vr1 = ArvT + (size_t)c1 * (BB * NN) + b * NN;
        const __bf16* tv0 = vT + (size_t)b * DD * NN + (size_t)c0 * NN;
        const __bf16* tv1 = vT + (size_t)b * DD * NN + (size_t)c1 * NN;
        f32x4 zz = {0.f,0.f,0.f,0.f};
        f32x4 T00 = zz, T01 = zz, T10 = zz, T11 = zz;   // T{i}{tile}
        f32x4 B00 = zz, B01 = zz, B10 = zz, B11 = zz;   // B{i}{tile}
#pragma unroll
        for (int ks = 0; ks < 12; ++ks) {
            int j0 = ks * 32 + lg * 8;
            bf16x8 ef0 = *(const bf16x8*)&eAbf[0][(lr & 7) * EA_ST + j0];
            bf16x8 ef1 = *(const bf16x8*)&eAbf[1][(lr & 7) * EA_ST + j0];
            bf16x8 av0 = *(const bf16x8*)(vr0 + j0);
            bf16x8 av1 = *(const bf16x8*)(vr1 + j0);
            bf16x8 w0  = *(const bf16x8*)(tv0 + j0);
            bf16x8 w1  = *(const bf16x8*)(tv1 + j0);
            T00 = mfma16(ef0, hid8s(av0, ap00), T00);
            T01 = mfma16(ef0, hid8s(av1, ap01), T01);
            T10 = mfma16(ef1, hid8s(av0, ap10), T10);
            T11 = mfma16(ef1, hid8s(av1, ap11), T11);
            B00 = mfma16(ef0, w0, B00);
            B01 = mfma16(ef0, w1, B01);
            B10 = mfma16(ef1, w0, B10);
            B11 = mfma16(ef1, w1, B11);
        }
        if (lg < 2) {
#pragma unroll
            for (int r = 0; r < 4; ++r) {
                int h = lg * 4 + r;
                Tl[0][h * T_ST + c0] = T00[r];
                Tl[0][h * T_ST + c1] = T01[r];
                Tl[1][h * T_ST + c0] = T10[r];
                Tl[1][h * T_ST + c1] = T11[r];
            }
        }
        // base extraction: tile0 cols = heads wv>>1, tile1 cols = heads 4+(wv>>1)
        int hp0 = wv >> 1, hp1 = (wv + 8) >> 1;
        int dcol = (wv & 1) * 16 + lr;
        if (lg == (hp0 >> 2)) {
            int r = hp0 & 3;
            float v0 = (r == 0) ? B00[0] : (r == 1) ? B00[1] : (r == 2) ? B00[2] : B00[3];
            float v1 = (r == 0) ? B10[0] : (r == 1) ? B10[1] : (r == 2) ? B10[2] : B10[3];
            basep[0][hp0 * 32 + dcol] = v0;
            basep[1][hp0 * 32 + dcol] = v1;
        }
        if (lg == (hp1 >> 2)) {
            int r = hp1 & 3;
            float v0 = (r == 0) ? B01[0] : (r == 1) ? B01[1] : (r == 2) ? B01[2] : B01[3];
            float v1 = (r == 0) ? B11[0] : (r == 1) ? B11[1] : (r == 2) ? B11[2] : B11[3];
            basep[0][hp1 * 32 + dcol] = v0;
            basep[1][hp1 * 32 + dcol] = v1;
        }
    }
    __syncthreads();

    // ---- epilogue: rc = T @ rv_w2^T; out = (rc + base)/Z + rv_b2 ----
    {
        int o = tid & 255, ii = tid >> 8;
        int h = o >> 5;
        float z = 0.f;
#pragma unroll
        for (int w = 0; w < 8; ++w) z += redsum[w][ii][h];
        const float4* w2p = (const float4*)(rv_w2 + (size_t)o * DD);
        float a = 0.f;
#pragma unroll 4
        for (int cc = 0; cc < 64; ++cc) {
            float4 wv4 = w2p[cc];
            float4 tv = *(const float4*)&Tl[ii][h * T_ST + cc * 4];
            a += wv4.x * tv.x + wv4.y * tv.y + wv4.z * tv.z + wv4.w * tv.w;
        }
        out[((size_t)(b * NN) + i0 + ii) * DD + o] =
            (a + basep[ii][o]) * __builtin_amdgcn_rcpf(z) + rv_b2[o];
    }
}

extern "C" void kernel_launch(void* const* d_in, const int* in_sizes, int n_in,
                              void* d_out, int out_size, void* d_ws, size_t ws_size,
                              hipStream_t stream) {
    const float* x      = (const float*)d_in[0];
    const float* coords = (const float*)d_in[1];
    const float* qkv_w  = (const float*)d_in[2];
    const float* qkv_b  = (const float*)d_in[3];
    const float* rb_w1  = (const float*)d_in[4];
    const float* rb_b1  = (const float*)d_in[5];
    const float* rb_w2  = (const float*)d_in[6];
    const float* rb_b2  = (const float*)d_in[7];
    const float* rv_w1  = (const float*)d_in[8];
    const float* rv_b1  = (const float*)d_in[9];
    const float* rv_w2  = (const float*)d_in[10];
    const float* rv_b2  = (const float*)d_in[11];
    float* out = (float*)d_out;

    float* ws = (float*)d_ws;
    const int PER = BB * NN * DD;          // 196608
    float* qb = ws;                        // f32
    __bf16* bfb  = (__bf16*)(ws + PER);
    __bf16* kbbf = bfb;                    // PER bf16
    __bf16* vTb  = bfb + PER;              // PER bf16
    __bf16* Arb  = bfb + 2 * PER;          // PER bf16
    __bf16* ArvT = bfb + 3 * PER;          // PER bf16

    pre_kernel<<<BB * NN, 256, 0, stream>>>(coords, rb_w1, rv_w1, Arb, ArvT);
    qkv_kernel<<<(BB * NN) / 4, 256, 0, stream>>>(x, qkv_w, qkv_b, qb, kbbf, vTb);
    attn_kernel<<<(BB * NN) / 2, 512, 0, stream>>>(
        rb_b1, rb_w2, rb_b2, rv_b1, rv_w2, rv_b2,
        qb, kbbf, vTb, Arb, ArvT, out);
}

// Round 4
// 108.170 us; speedup vs baseline: 1.6201x; 1.0950x over previous
//
#include <hip/hip_runtime.h>
#include <math.h>

#define BB 2
#define NN 384
#define DD 256
#define HH 8
#define RN (BB * NN)   // 768
#define INV_SQRT_HD 0.17677669529663687f   // 1/sqrt(32)
#define LOG2E 1.4426950408889634f
#define NLN2 -0.6931471805599453f

#define W2_ST 264   // bf16 stride, rb_w2 rows
#define EA_ST 392   // bf16 stride, e A-frag rows
#define T_ST  264   // f32 stride, T rows

typedef float f32x4 __attribute__((ext_vector_type(4)));
typedef __bf16 bf16x8 __attribute__((ext_vector_type(8)));
typedef __bf16 bf16x4 __attribute__((ext_vector_type(4)));

__device__ __forceinline__ f32x4 mfma16(bf16x8 a, bf16x8 b, f32x4 c) {
    return __builtin_amdgcn_mfma_f32_16x16x32_bf16(a, b, c, 0, 0, 0);
}

// d = av' - ap'  where primes are pre-scaled by log2e, i.e. d = -x*log2e.
// returns -log2e * silu(x); the *(-ln2) is folded into w2bf / Tl downstream.
__device__ __forceinline__ float hidp(float d) {
    float e = __builtin_amdgcn_exp2f(d);              // = exp(-x)
    return d * __builtin_amdgcn_rcpf(1.0f + e);       // = -log2e * x * sigmoid(x)
}
__device__ __forceinline__ bf16x8 hid8(bf16x8 av, float4 a0, float4 a1) {
    bf16x8 r;
    r[0] = (__bf16)hidp((float)av[0] - a0.x);
    r[1] = (__bf16)hidp((float)av[1] - a0.y);
    r[2] = (__bf16)hidp((float)av[2] - a0.z);
    r[3] = (__bf16)hidp((float)av[3] - a0.w);
    r[4] = (__bf16)hidp((float)av[4] - a1.x);
    r[5] = (__bf16)hidp((float)av[5] - a1.y);
    r[6] = (__bf16)hidp((float)av[6] - a1.z);
    r[7] = (__bf16)hidp((float)av[7] - a1.w);
    return r;
}
__device__ __forceinline__ bf16x8 hid8s(bf16x8 av, float a) {
    bf16x8 r;
#pragma unroll
    for (int q = 0; q < 8; ++q) r[q] = (__bf16)hidp((float)av[q] - a);
    return r;
}
__device__ __forceinline__ bf16x8 pack8(float4 a, float4 b) {
    bf16x8 r;
    r[0] = (__bf16)a.x; r[1] = (__bf16)a.y; r[2] = (__bf16)a.z; r[3] = (__bf16)a.w;
    r[4] = (__bf16)b.x; r[5] = (__bf16)b.y; r[6] = (__bf16)b.z; r[7] = (__bf16)b.w;
    return r;
}

// ---------------- Kernel 1: fused prep ----------------
// blocks [0,576): qkv via MFMA.  blocks [576,1344): A-array precompute.
// q: f32 [768][256] pre-scaled by 1/sqrt(32); k: bf16 [768][256];
// vT: bf16 [b][256(hd)][384(n)]
// Arb[r][c] = (coords_r . rb_w1_c)*log2e   (bf16, [768][256])
// ArvT[c][r] = (coords_r . rv_w1_c)*log2e  (bf16, [256][768])
__global__ __launch_bounds__(256) void prep_kernel(
    const float* __restrict__ x, const float* __restrict__ coords,
    const float* __restrict__ qkv_w, const float* __restrict__ qkv_b,
    const float* __restrict__ rb_w1, const float* __restrict__ rv_w1,
    float* __restrict__ qb, __bf16* __restrict__ kbbf, __bf16* __restrict__ vT,
    __bf16* __restrict__ Arb, __bf16* __restrict__ ArvT)
{
    int bid = blockIdx.x, tid = threadIdx.x;
    if (bid >= 576) {
        int r = bid - 576, c = tid;
        float cx = coords[r * 3 + 0], cy = coords[r * 3 + 1], cz = coords[r * 3 + 2];
        float ab = (cx * rb_w1[c * 3] + cy * rb_w1[c * 3 + 1] + cz * rb_w1[c * 3 + 2]) * LOG2E;
        float av = (cx * rv_w1[c * 3] + cy * rv_w1[c * 3 + 1] + cz * rv_w1[c * 3 + 2]) * LOG2E;
        Arb[r * DD + c] = (__bf16)ab;
        ArvT[c * RN + r] = (__bf16)av;
        return;
    }
    // qkv: M=768 (rows), N=768 (outs), K=256. 16x16 tile per wave.
    int mt = bid % 48, nb = bid / 48;
    int w = tid >> 6, l = tid & 63, lr = l & 15, lg = l >> 4;
    int m0 = mt * 16, n0 = nb * 64 + w * 16;
    const float* xr = x + (size_t)(m0 + lr) * DD;
    const float* wr = qkv_w + (size_t)(n0 + lr) * DD;
    f32x4 acc = {0.f, 0.f, 0.f, 0.f};
#pragma unroll
    for (int ks = 0; ks < 8; ++ks) {
        int c0 = ks * 32 + lg * 8;
        float4 xa = *(const float4*)(xr + c0);
        float4 xb = *(const float4*)(xr + c0 + 4);
        float4 wa = *(const float4*)(wr + c0);
        float4 wb = *(const float4*)(wr + c0 + 4);
        acc = mfma16(pack8(xa, xb), pack8(wa, wb), acc);
    }
    int col = n0 + lr;
    float bo = qkv_b[col];
    int part = col >> 8, o = col & 255;
#pragma unroll
    for (int r = 0; r < 4; ++r) {
        int m = m0 + lg * 4 + r;
        float v = acc[r] + bo;
        if (part == 0) {
            qb[(size_t)m * DD + o] = v * INV_SQRT_HD;
        } else if (part == 1) {
            kbbf[(size_t)m * DD + o] = (__bf16)v;
        } else {
            int b = (m >= NN) ? 1 : 0;
            int n = m - b * NN;
            vT[(size_t)b * DD * NN + (size_t)o * NN + n] = (__bf16)v;
        }
    }
}

// ---------------- Kernel 2: fused attention, 1 i per block, 768 blocks ----------------
__global__ __launch_bounds__(512, 6) void attn_kernel(
    const float* __restrict__ rb_b1, const float* __restrict__ rb_w2,
    const float* __restrict__ rb_b2,
    const float* __restrict__ rv_b1, const float* __restrict__ rv_w2,
    const float* __restrict__ rv_b2,
    const float* __restrict__ qb, const __bf16* __restrict__ kbbf,
    const __bf16* __restrict__ vT,
    const __bf16* __restrict__ Arb, const __bf16* __restrict__ ArvT,
    float* __restrict__ out)
{
    __shared__ __align__(16) __bf16 qsbf[DD];
    __shared__ __align__(16) float Apr[DD];
    __shared__ __align__(16) float Apv[DD];
    __shared__ __align__(16) __bf16 w2bf[HH * W2_ST];
    __shared__ __align__(16) __bf16 eAbf[HH * EA_ST];
    __shared__ __align__(16) float Tl[HH * T_ST];
    __shared__ __align__(16) float basep[DD];
    __shared__ float redsum[8][HH];

    int tid = threadIdx.x;
    int bx = blockIdx.x;
    int b = bx / NN, i = bx - b * NN;
    int gi = b * NN + i;

    // ---- setup ----
    if (tid < 256) {
        qsbf[tid] = (__bf16)qb[(size_t)gi * DD + tid];
        Apr[tid] = (float)Arb[(size_t)gi * DD + tid] + rb_b1[tid] * LOG2E;
        Apv[tid] = (float)ArvT[(size_t)tid * RN + gi] + rv_b1[tid] * LOG2E;
    }
    for (int idx = tid; idx < HH * 256; idx += 512)
        w2bf[(idx >> 8) * W2_ST + (idx & 255)] = (__bf16)(rb_w2[idx] * NLN2);
    __syncthreads();

    int l = tid & 63, wv = tid >> 6;
    int lr = l & 15, lg = l >> 4;
    float rb2l = rb_b2[lr & 7];

    // ---- phase 1: scores = rel_bias (hid'@w2') + QK (block-diag MFMA) ----
    {
        const __bf16* arbB = Arb + (size_t)b * NN * DD;
        const __bf16* kbB  = kbbf + (size_t)b * NN * DD;
        const __bf16* ar0 = arbB + ((wv      ) * 16 + lr) * DD;
        const __bf16* ar1 = arbB + ((wv +  8) * 16 + lr) * DD;
        const __bf16* ar2 = arbB + ((wv + 16) * 16 + lr) * DD;
        const __bf16* kr0 = kbB  + ((wv      ) * 16 + lr) * DD;
        const __bf16* kr1 = kbB  + ((wv +  8) * 16 + lr) * DD;
        const __bf16* kr2 = kbB  + ((wv + 16) * 16 + lr) * DD;
        f32x4 a0 = {0.f, 0.f, 0.f, 0.f}, a1 = a0, a2 = a0;
#pragma unroll
        for (int ks = 0; ks < 8; ++ks) {
            int c0 = ks * 32 + lg * 8;
            float4 p0 = *(const float4*)&Apr[c0];
            float4 p1 = *(const float4*)&Apr[c0 + 4];
            bf16x8 wf = *(const bf16x8*)&w2bf[(lr & 7) * W2_ST + c0];
            bf16x8 v0 = *(const bf16x8*)(ar0 + c0);
            bf16x8 v1 = *(const bf16x8*)(ar1 + c0);
            bf16x8 v2 = *(const bf16x8*)(ar2 + c0);
            bf16x8 k0 = *(const bf16x8*)(kr0 + c0);
            bf16x8 k1 = *(const bf16x8*)(kr1 + c0);
            bf16x8 k2 = *(const bf16x8*)(kr2 + c0);
            bf16x8 qf;
            if (lr == ks) {
                qf = *(const bf16x8*)&qsbf[c0];
            } else {
#pragma unroll
                for (int e = 0; e < 8; ++e) qf[e] = (__bf16)0.f;
            }
            a0 = mfma16(hid8(v0, p0, p1), wf, a0);
            a1 = mfma16(hid8(v1, p0, p1), wf, a1);
            a2 = mfma16(hid8(v2, p0, p1), wf, a2);
            a0 = mfma16(k0, qf, a0);
            a1 = mfma16(k1, qf, a1);
            a2 = mfma16(k2, qf, a2);
        }
        // e = exp(score + rb_b2); Z partials; e (bf16) -> LDS A-frag rows
        float z = 0.f;
#define FINTILE(ACC, T) { \
            float e0 = __expf(ACC[0] + rb2l); \
            float e1 = __expf(ACC[1] + rb2l); \
            float e2 = __expf(ACC[2] + rb2l); \
            float e3 = __expf(ACC[3] + rb2l); \
            if (lr < 8) { \
                bf16x4 ev; \
                ev[0] = (__bf16)e0; ev[1] = (__bf16)e1; \
                ev[2] = (__bf16)e2; ev[3] = (__bf16)e3; \
                *(bf16x4*)&eAbf[lr * EA_ST + ((T) * 8 + wv) * 16 + lg * 4] = ev; \
            } \
            float zs = e0 + e1 + e2 + e3; \
            zs += __shfl_xor(zs, 16); \
            zs += __shfl_xor(zs, 32); \
            z += zs; }
        FINTILE(a0, 0)
        FINTILE(a1, 1)
        FINTILE(a2, 2)
#undef FINTILE
        if (lg == 0 && lr < 8) redsum[wv][lr] = z;
    }
    __syncthreads();

    // ---- phase 2: T[h][c] (hid') and base[h][d] (vT) via MFMA, K = j ----
    {
        int c0 = wv * 16 + lr, c1 = c0 + 128;
        float ap0 = Apv[c0], ap1 = Apv[c1];
        const __bf16* vr0 = ArvT + (size_t)c0 * RN + b * NN;
        const __bf16* vr1 = ArvT + (size_t)c1 * RN + b * NN;
        const __bf16* tv0 = vT + (size_t)b * DD * NN + (size_t)c0 * NN;
        const __bf16* tv1 = vT + (size_t)b * DD * NN + (size_t)c1 * NN;
        f32x4 T0 = {0.f, 0.f, 0.f, 0.f}, T1 = T0, B0 = T0, B1 = T0;
#pragma unroll
        for (int ks = 0; ks < 12; ++ks) {
            int j0 = ks * 32 + lg * 8;
            bf16x8 ef  = *(const bf16x8*)&eAbf[(lr & 7) * EA_ST + j0];
            bf16x8 av0 = *(const bf16x8*)(vr0 + j0);
            bf16x8 av1 = *(const bf16x8*)(vr1 + j0);
            bf16x8 w0  = *(const bf16x8*)(tv0 + j0);
            bf16x8 w1  = *(const bf16x8*)(tv1 + j0);
            T0 = mfma16(ef, hid8s(av0, ap0), T0);
            T1 = mfma16(ef, hid8s(av1, ap1), T1);
            B0 = mfma16(ef, w0, B0);
            B1 = mfma16(ef, w1, B1);
        }
        if (lg < 2) {
#pragma unroll
            for (int r = 0; r < 4; ++r) {
                int h = lg * 4 + r;
                Tl[h * T_ST + c0] = T0[r] * NLN2;
                Tl[h * T_ST + c1] = T1[r] * NLN2;
            }
        }
        // base extraction: D[row=h][col=c]; needed h = c>>5
        int h0 = wv >> 1, h1 = 4 + (wv >> 1);
        int dcol = (wv & 1) * 16 + lr;
        if (lg == (h0 >> 2)) {
            int r = h0 & 3;
            basep[h0 * 32 + dcol] = (r == 0) ? B0[0] : (r == 1) ? B0[1] : (r == 2) ? B0[2] : B0[3];
        }
        if (lg == (h1 >> 2)) {
            int r = h1 & 3;
            basep[h1 * 32 + dcol] = (r == 0) ? B1[0] : (r == 1) ? B1[1] : (r == 2) ? B1[2] : B1[3];
        }
    }
    __syncthreads();

    // ---- epilogue: rc = T @ rv_w2^T; out = (rc + base)/Z + rv_b2 ----
    if (tid < 256) {
        int o = tid, h = o >> 5;
        float z = 0.f;
#pragma unroll
        for (int w = 0; w < 8; ++w) z += redsum[w][h];
        const float4* w2p = (const float4*)(rv_w2 + (size_t)o * DD);
        float a = 0.f;
#pragma unroll 4
        for (int cc = 0; cc < 64; ++cc) {
            float4 wv4 = w2p[cc];
            float4 tv = *(const float4*)&Tl[h * T_ST + cc * 4];
            a += wv4.x * tv.x + wv4.y * tv.y + wv4.z * tv.z + wv4.w * tv.w;
        }
        out[(size_t)gi * DD + o] = (a + basep[o]) * __builtin_amdgcn_rcpf(z) + rv_b2[o];
    }
}

extern "C" void kernel_launch(void* const* d_in, const int* in_sizes, int n_in,
                              void* d_out, int out_size, void* d_ws, size_t ws_size,
                              hipStream_t stream) {
    const float* x      = (const float*)d_in[0];
    const float* coords = (const float*)d_in[1];
    const float* qkv_w  = (const float*)d_in[2];
    const float* qkv_b  = (const float*)d_in[3];
    const float* rb_w1  = (const float*)d_in[4];
    const float* rb_b1  = (const float*)d_in[5];
    const float* rb_w2  = (const float*)d_in[6];
    const float* rb_b2  = (const float*)d_in[7];
    const float* rv_w1  = (const float*)d_in[8];
    const float* rv_b1  = (const float*)d_in[9];
    const float* rv_w2  = (const float*)d_in[10];
    const float* rv_b2  = (const float*)d_in[11];
    float* out = (float*)d_out;

    float* ws = (float*)d_ws;
    const int PER = RN * DD;               // 196608
    float* qb = ws;                        // f32
    __bf16* bfb  = (__bf16*)(ws + PER);
    __bf16* kbbf = bfb;                    // PER bf16
    __bf16* vTb  = bfb + PER;              // PER bf16
    __bf16* Arb  = bfb + 2 * PER;          // PER bf16
    __bf16* ArvT = bfb + 3 * PER;          // PER bf16

    prep_kernel<<<576 + RN, 256, 0, stream>>>(x, coords, qkv_w, qkv_b,
                                              rb_w1, rv_w1, qb, kbbf, vTb, Arb, ArvT);
    attn_kernel<<<RN, 512, 0, stream>>>(
        rb_b1, rb_w2, rb_b2, rv_b1, rv_w2, rv_b2,
        qb, kbbf, vTb, Arb, ArvT, out);
}